// Round 1
// baseline (1757.362 us; speedup 1.0000x reference)
//
#include <hip/hip_runtime.h>
#include <math.h>

// GCN 2-layer: out = Anorm( relu( Anorm(X W1) + b1 ) W2 ) + b2
// Anorm = D^-1/2 (A+I) D^-1/2, deg over dst (+1 self loop).
//
// Pipeline (all fp32):
//  1. deg[i]=1; atomic count dst; dinv=rsqrt(deg)
//  2. h1 = X @ W1                          (LDS-tiled vector GEMM)
//  3. ag1[i] = h1[i]*dinv[i]^2 + b1        (self loop + bias, full init)
//  4. ag1[dst] += h1[src]*dinv[s]*dinv[d]  (edge scatter, f32 atomics)
//  5. h2 = relu(ag1) @ W2                  (relu fused into A-tile load)
//  6. out[i] = h2[i]*dinv[i]^2 + b2
//  7. out[dst] += h2[src]*norm

__global__ void k_deg_init(float* __restrict__ deg, int n) {
  int i = blockIdx.x * blockDim.x + threadIdx.x;
  if (i < n) deg[i] = 1.0f;  // self loop
}

__global__ void k_deg_count(const int* __restrict__ dst, float* __restrict__ deg, int E) {
  int e = blockIdx.x * blockDim.x + threadIdx.x;
  if (e < E) atomicAdd(&deg[dst[e]], 1.0f);
}

__global__ void k_rsqrt_inplace(float* __restrict__ deg, int n) {
  int i = blockIdx.x * blockDim.x + threadIdx.x;
  if (i < n) deg[i] = rsqrtf(deg[i]);
}

// C[M,N] = op(A)[M,K] @ W[K,N], row-major. op = relu if RELU.
// 64-row A tile staged in LDS (32 KB); W streamed from global (L1/L2 hot).
template<int K, int N, bool RELU>
__global__ __launch_bounds__(256) void k_gemm(const float* __restrict__ A,
                                              const float* __restrict__ W,
                                              float* __restrict__ C, int M) {
  __shared__ float As[64][K];
  const int tid = threadIdx.x;
  const int row0 = blockIdx.x * 64;
  constexpr int KQ = K / 4;

  for (int i = tid; i < 64 * KQ; i += 256) {
    int r = i / KQ, cq = i % KQ;
    float4 v = make_float4(0.f, 0.f, 0.f, 0.f);
    if (row0 + r < M)
      v = reinterpret_cast<const float4*>(A)[(size_t)(row0 + r) * KQ + cq];
    if (RELU) {
      v.x = fmaxf(v.x, 0.f); v.y = fmaxf(v.y, 0.f);
      v.z = fmaxf(v.z, 0.f); v.w = fmaxf(v.w, 0.f);
    }
    reinterpret_cast<float4*>(&As[r][0])[cq] = v;
  }
  __syncthreads();

  constexpr int NQ = N / 4;              // float4 columns
  constexpr int ROWS = 64 / (256 / NQ);  // rows per thread (8 for N=128, 4 for N=64)
  const int tx = tid % NQ;
  const int ty = tid / NQ;
  const int rbase = ty * ROWS;

  float4 acc[ROWS];
#pragma unroll
  for (int r = 0; r < ROWS; ++r) acc[r] = make_float4(0.f, 0.f, 0.f, 0.f);

  for (int k = 0; k < K; k += 4) {
    float4 w0 = reinterpret_cast<const float4*>(W)[(size_t)(k + 0) * NQ + tx];
    float4 w1 = reinterpret_cast<const float4*>(W)[(size_t)(k + 1) * NQ + tx];
    float4 w2 = reinterpret_cast<const float4*>(W)[(size_t)(k + 2) * NQ + tx];
    float4 w3 = reinterpret_cast<const float4*>(W)[(size_t)(k + 3) * NQ + tx];
#pragma unroll
    for (int r = 0; r < ROWS; ++r) {
      float4 a = *reinterpret_cast<const float4*>(&As[rbase + r][k]);
      acc[r].x = fmaf(a.x, w0.x, acc[r].x);
      acc[r].y = fmaf(a.x, w0.y, acc[r].y);
      acc[r].z = fmaf(a.x, w0.z, acc[r].z);
      acc[r].w = fmaf(a.x, w0.w, acc[r].w);
      acc[r].x = fmaf(a.y, w1.x, acc[r].x);
      acc[r].y = fmaf(a.y, w1.y, acc[r].y);
      acc[r].z = fmaf(a.y, w1.z, acc[r].z);
      acc[r].w = fmaf(a.y, w1.w, acc[r].w);
      acc[r].x = fmaf(a.z, w2.x, acc[r].x);
      acc[r].y = fmaf(a.z, w2.y, acc[r].y);
      acc[r].z = fmaf(a.z, w2.z, acc[r].z);
      acc[r].w = fmaf(a.z, w2.w, acc[r].w);
      acc[r].x = fmaf(a.w, w3.x, acc[r].x);
      acc[r].y = fmaf(a.w, w3.y, acc[r].y);
      acc[r].z = fmaf(a.w, w3.z, acc[r].z);
      acc[r].w = fmaf(a.w, w3.w, acc[r].w);
    }
  }

#pragma unroll
  for (int r = 0; r < ROWS; ++r) {
    int row = row0 + rbase + r;
    if (row < M)
      reinterpret_cast<float4*>(C)[(size_t)row * NQ + tx] = acc[r];
  }
}

// out[i,:] = h[i,:] * dinv[i]^2 + b  (initializes the whole buffer)
template<int C>
__global__ void k_selfinit(const float* __restrict__ h, const float* __restrict__ dinv,
                           const float* __restrict__ b, float* __restrict__ out, int n) {
  constexpr int CQ = C / 4;
  int idx = blockIdx.x * blockDim.x + threadIdx.x;
  if (idx >= n * CQ) return;
  int i = idx / CQ;
  int q = idx % CQ;
  float di = dinv[i];
  float s = di * di;
  float4 v = reinterpret_cast<const float4*>(h)[idx];
  float4 bb = reinterpret_cast<const float4*>(b)[q];
  float4 o;
  o.x = fmaf(v.x, s, bb.x);
  o.y = fmaf(v.y, s, bb.y);
  o.z = fmaf(v.z, s, bb.z);
  o.w = fmaf(v.w, s, bb.w);
  reinterpret_cast<float4*>(out)[idx] = o;
}

// out[dst[e],:] += h[src[e],:] * dinv[s]*dinv[d]   — one thread per (edge, 4-ch quad)
template<int C>
__global__ void k_scatter(const float* __restrict__ h, const float* __restrict__ dinv,
                          const int* __restrict__ src, const int* __restrict__ dst,
                          float* __restrict__ out, int E) {
  constexpr int CQ = C / 4;
  int idx = blockIdx.x * blockDim.x + threadIdx.x;
  if (idx >= E * CQ) return;
  int e = idx / CQ;
  int q = idx % CQ;
  int s = src[e];
  int d = dst[e];
  float norm = dinv[s] * dinv[d];
  float4 v = reinterpret_cast<const float4*>(h)[(size_t)s * CQ + q];
  float* o = out + (size_t)d * C + q * 4;
  atomicAdd(o + 0, v.x * norm);
  atomicAdd(o + 1, v.y * norm);
  atomicAdd(o + 2, v.z * norm);
  atomicAdd(o + 3, v.w * norm);
}

extern "C" void kernel_launch(void* const* d_in, const int* in_sizes, int n_in,
                              void* d_out, int out_size, void* d_ws, size_t ws_size,
                              hipStream_t stream) {
  const float* x  = (const float*)d_in[0];
  const float* W1 = (const float*)d_in[1];
  const float* b1 = (const float*)d_in[2];
  const float* W2 = (const float*)d_in[3];
  const float* b2 = (const float*)d_in[4];
  const int* src  = (const int*)d_in[5];
  const int* dst  = (const int*)d_in[6];
  float* out = (float*)d_out;

  constexpr int IN_C = 128, HID_C = 128, OUT_C = 64;
  const int N = in_sizes[0] / IN_C;   // 100000
  const int E = in_sizes[5];          // 600000

  // workspace layout (floats)
  float* dinv = (float*)d_ws;                    // N (deg, then rsqrt in place)
  size_t off = ((size_t)N + 1023) & ~(size_t)1023;
  float* h1  = dinv + off;                       // N*128
  float* ag1 = h1 + (size_t)N * HID_C;           // N*128
  float* h2  = ag1 + (size_t)N * HID_C;          // N*64

  const int T = 256;

  // 1. degrees
  k_deg_init<<<(N + T - 1) / T, T, 0, stream>>>(dinv, N);
  k_deg_count<<<(E + T - 1) / T, T, 0, stream>>>(dst, dinv, E);
  k_rsqrt_inplace<<<(N + T - 1) / T, T, 0, stream>>>(dinv, N);

  // 2. h1 = X @ W1
  k_gemm<IN_C, HID_C, false><<<(N + 63) / 64, T, 0, stream>>>(x, W1, h1, N);

  // 3. ag1 = h1*dinv^2 + b1 ; 4. edge scatter
  {
    int total = N * (HID_C / 4);
    k_selfinit<HID_C><<<(total + T - 1) / T, T, 0, stream>>>(h1, dinv, b1, ag1, N);
    int etotal = E * (HID_C / 4);
    k_scatter<HID_C><<<(etotal + T - 1) / T, T, 0, stream>>>(h1, dinv, src, dst, ag1, E);
  }

  // 5. h2 = relu(ag1) @ W2
  k_gemm<HID_C, OUT_C, true><<<(N + 63) / 64, T, 0, stream>>>(ag1, W2, h2, N);

  // 6. out = h2*dinv^2 + b2 ; 7. edge scatter
  {
    int total = N * (OUT_C / 4);
    k_selfinit<OUT_C><<<(total + T - 1) / T, T, 0, stream>>>(h2, dinv, b2, out, N);
    int etotal = E * (OUT_C / 4);
    k_scatter<OUT_C><<<(etotal + T - 1) / T, T, 0, stream>>>(h2, dinv, src, dst, out, E);
  }
}

// Round 2
// 340.270 us; speedup vs baseline: 5.1646x; 5.1646x over previous
//
#include <hip/hip_runtime.h>
#include <math.h>

// GCN 2-layer: out = Anorm( relu( Anorm(X W1) + b1 ) W2 ) + b2
// Anorm = D^-1/2 (A+I) D^-1/2, deg = indeg(dst) + 1.
//
// R2: replaced f32 atomic scatter (1010+505 us, 4x write amplification) with
// on-device CSR build (histogram -> scan -> bucket fill) + register-gather
// aggregation. Self-loop+bias fused into aggregation init.

// ---------------- CSR build ----------------

__global__ void k_zero_i32(int* __restrict__ p, int n) {
  int i = blockIdx.x * blockDim.x + threadIdx.x;
  if (i < n) p[i] = 0;
}

__global__ void k_count(const int* __restrict__ dst, int* __restrict__ counts, int E) {
  int e = blockIdx.x * blockDim.x + threadIdx.x;
  if (e < E) atomicAdd(&counts[dst[e]], 1);
}

// dinv[i] = rsqrt(counts[i] + 1)
__global__ void k_dinv(const int* __restrict__ counts, float* __restrict__ dinv, int n) {
  int i = blockIdx.x * blockDim.x + threadIdx.x;
  if (i < n) dinv[i] = rsqrtf((float)(counts[i] + 1));
}

// Exclusive scan of counts[0..n) into offsets[0..n), chunked 1024/block.
constexpr int SCAN_CHUNK = 1024;

__global__ __launch_bounds__(256) void k_scan1(const int* __restrict__ counts,
                                               int* __restrict__ offsets,
                                               int* __restrict__ aux, int n) {
  __shared__ int tsum[256];
  int tid = threadIdx.x;
  int base = blockIdx.x * SCAN_CHUNK + tid * 4;
  int v0 = (base + 0 < n) ? counts[base + 0] : 0;
  int v1 = (base + 1 < n) ? counts[base + 1] : 0;
  int v2 = (base + 2 < n) ? counts[base + 2] : 0;
  int v3 = (base + 3 < n) ? counts[base + 3] : 0;
  int s = v0 + v1 + v2 + v3;
  tsum[tid] = s;
  __syncthreads();
  for (int off = 1; off < 256; off <<= 1) {
    int t = (tid >= off) ? tsum[tid - off] : 0;
    __syncthreads();
    tsum[tid] += t;
    __syncthreads();
  }
  int excl = tsum[tid] - s;  // exclusive prefix within block
  if (base + 0 < n) offsets[base + 0] = excl;
  if (base + 1 < n) offsets[base + 1] = excl + v0;
  if (base + 2 < n) offsets[base + 2] = excl + v0 + v1;
  if (base + 3 < n) offsets[base + 3] = excl + v0 + v1 + v2;
  if (tid == 255) aux[blockIdx.x] = tsum[255];
}

// single block: exclusive scan of aux[0..G) into auxs[0..G), G <= 256
__global__ __launch_bounds__(256) void k_scan2(const int* __restrict__ aux,
                                               int* __restrict__ auxs, int G) {
  __shared__ int tsum[256];
  int tid = threadIdx.x;
  int v = (tid < G) ? aux[tid] : 0;
  tsum[tid] = v;
  __syncthreads();
  for (int off = 1; off < 256; off <<= 1) {
    int t = (tid >= off) ? tsum[tid - off] : 0;
    __syncthreads();
    tsum[tid] += t;
    __syncthreads();
  }
  if (tid < G) auxs[tid] = tsum[tid] - v;
}

// offsets[i] += auxs[chunk]; cursor[i] = final; thread 0 writes offsets[n] = E
__global__ void k_scan3(int* __restrict__ offsets, const int* __restrict__ auxs,
                        int* __restrict__ cursor, int n, int E) {
  int i = blockIdx.x * blockDim.x + threadIdx.x;
  if (i < n) {
    int v = offsets[i] + auxs[i / SCAN_CHUNK];
    offsets[i] = v;
    cursor[i] = v;
  }
  if (i == 0) offsets[n] = E;
}

// bucket fill: esrc/enorm sorted by dst
__global__ void k_fill(const int* __restrict__ src, const int* __restrict__ dst,
                       const float* __restrict__ dinv, int* __restrict__ cursor,
                       int* __restrict__ esrc, float* __restrict__ enorm, int E) {
  int e = blockIdx.x * blockDim.x + threadIdx.x;
  if (e >= E) return;
  int s = src[e];
  int d = dst[e];
  int pos = atomicAdd(&cursor[d], 1);
  esrc[pos] = s;
  enorm[pos] = dinv[s] * dinv[d];
}

// ---------------- GEMM (fp32 vector, LDS A-tile) ----------------

template<int K, int N, bool RELU>
__global__ __launch_bounds__(256) void k_gemm(const float* __restrict__ A,
                                              const float* __restrict__ W,
                                              float* __restrict__ C, int M) {
  __shared__ float As[64][K];
  const int tid = threadIdx.x;
  const int row0 = blockIdx.x * 64;
  constexpr int KQ = K / 4;

  for (int i = tid; i < 64 * KQ; i += 256) {
    int r = i / KQ, cq = i % KQ;
    float4 v = make_float4(0.f, 0.f, 0.f, 0.f);
    if (row0 + r < M)
      v = reinterpret_cast<const float4*>(A)[(size_t)(row0 + r) * KQ + cq];
    if (RELU) {
      v.x = fmaxf(v.x, 0.f); v.y = fmaxf(v.y, 0.f);
      v.z = fmaxf(v.z, 0.f); v.w = fmaxf(v.w, 0.f);
    }
    reinterpret_cast<float4*>(&As[r][0])[cq] = v;
  }
  __syncthreads();

  constexpr int NQ = N / 4;
  constexpr int ROWS = 64 / (256 / NQ);
  const int tx = tid % NQ;
  const int ty = tid / NQ;
  const int rbase = ty * ROWS;

  float4 acc[ROWS];
#pragma unroll
  for (int r = 0; r < ROWS; ++r) acc[r] = make_float4(0.f, 0.f, 0.f, 0.f);

  for (int k = 0; k < K; k += 4) {
    float4 w0 = reinterpret_cast<const float4*>(W)[(size_t)(k + 0) * NQ + tx];
    float4 w1 = reinterpret_cast<const float4*>(W)[(size_t)(k + 1) * NQ + tx];
    float4 w2 = reinterpret_cast<const float4*>(W)[(size_t)(k + 2) * NQ + tx];
    float4 w3 = reinterpret_cast<const float4*>(W)[(size_t)(k + 3) * NQ + tx];
#pragma unroll
    for (int r = 0; r < ROWS; ++r) {
      float4 a = *reinterpret_cast<const float4*>(&As[rbase + r][k]);
      acc[r].x = fmaf(a.x, w0.x, acc[r].x);
      acc[r].y = fmaf(a.x, w0.y, acc[r].y);
      acc[r].z = fmaf(a.x, w0.z, acc[r].z);
      acc[r].w = fmaf(a.x, w0.w, acc[r].w);
      acc[r].x = fmaf(a.y, w1.x, acc[r].x);
      acc[r].y = fmaf(a.y, w1.y, acc[r].y);
      acc[r].z = fmaf(a.y, w1.z, acc[r].z);
      acc[r].w = fmaf(a.y, w1.w, acc[r].w);
      acc[r].x = fmaf(a.z, w2.x, acc[r].x);
      acc[r].y = fmaf(a.z, w2.y, acc[r].y);
      acc[r].z = fmaf(a.z, w2.z, acc[r].z);
      acc[r].w = fmaf(a.z, w2.w, acc[r].w);
      acc[r].x = fmaf(a.w, w3.x, acc[r].x);
      acc[r].y = fmaf(a.w, w3.y, acc[r].y);
      acc[r].z = fmaf(a.w, w3.z, acc[r].z);
      acc[r].w = fmaf(a.w, w3.w, acc[r].w);
    }
  }

#pragma unroll
  for (int r = 0; r < ROWS; ++r) {
    int row = row0 + rbase + r;
    if (row < M)
      reinterpret_cast<float4*>(C)[(size_t)row * NQ + tx] = acc[r];
  }
}

// ---------------- CSR gather aggregation ----------------
// out[i,:] = h[i,:]*dinv[i]^2 + b + sum_{e in row i} h[esrc[e],:]*enorm[e]
template<int C>
__global__ __launch_bounds__(256) void k_agg(const float* __restrict__ h,
                                             const float* __restrict__ dinv,
                                             const float* __restrict__ b,
                                             const int* __restrict__ offsets,
                                             const int* __restrict__ esrc,
                                             const float* __restrict__ enorm,
                                             float* __restrict__ out, int n) {
  constexpr int CQ = C / 4;       // threads per node
  constexpr int NPB = 256 / CQ;   // nodes per block
  const int tid = threadIdx.x;
  const int node = blockIdx.x * NPB + tid / CQ;
  const int q = tid % CQ;
  if (node >= n) return;

  float di = dinv[node];
  float s2 = di * di;
  float4 bb = reinterpret_cast<const float4*>(b)[q];
  float4 v = reinterpret_cast<const float4*>(h)[(size_t)node * CQ + q];
  float4 acc;
  acc.x = fmaf(v.x, s2, bb.x);
  acc.y = fmaf(v.y, s2, bb.y);
  acc.z = fmaf(v.z, s2, bb.z);
  acc.w = fmaf(v.w, s2, bb.w);

  int e0 = offsets[node];
  int e1 = offsets[node + 1];
  for (int e = e0; e < e1; ++e) {
    int s = esrc[e];
    float nrm = enorm[e];
    float4 hv = reinterpret_cast<const float4*>(h)[(size_t)s * CQ + q];
    acc.x = fmaf(hv.x, nrm, acc.x);
    acc.y = fmaf(hv.y, nrm, acc.y);
    acc.z = fmaf(hv.z, nrm, acc.z);
    acc.w = fmaf(hv.w, nrm, acc.w);
  }
  reinterpret_cast<float4*>(out)[(size_t)node * CQ + q] = acc;
}

// ---------------- launch ----------------

extern "C" void kernel_launch(void* const* d_in, const int* in_sizes, int n_in,
                              void* d_out, int out_size, void* d_ws, size_t ws_size,
                              hipStream_t stream) {
  const float* x  = (const float*)d_in[0];
  const float* W1 = (const float*)d_in[1];
  const float* b1 = (const float*)d_in[2];
  const float* W2 = (const float*)d_in[3];
  const float* b2 = (const float*)d_in[4];
  const int* src  = (const int*)d_in[5];
  const int* dst  = (const int*)d_in[6];
  float* out = (float*)d_out;

  constexpr int IN_C = 128, HID_C = 128, OUT_C = 64;
  const int N = in_sizes[0] / IN_C;   // 100000
  const int E = in_sizes[5];          // 600000

  // workspace layout (256B-aligned slabs)
  char* p = (char*)d_ws;
  auto alloc = [&](size_t bytes) {
    char* r = p;
    p += (bytes + 255) & ~(size_t)255;
    return r;
  };
  float* dinv    = (float*)alloc((size_t)N * 4);
  int*   offsets = (int*)alloc((size_t)(N + 1) * 4);
  int*   counts  = (int*)alloc((size_t)N * 4);
  int*   cursor  = (int*)alloc((size_t)N * 4);
  int*   aux     = (int*)alloc(1024);
  int*   auxs    = (int*)alloc(1024);
  int*   esrc    = (int*)alloc((size_t)E * 4);
  float* enorm   = (float*)alloc((size_t)E * 4);
  float* h1      = (float*)alloc((size_t)N * HID_C * 4);
  float* ag1     = (float*)alloc((size_t)N * HID_C * 4);
  float* h2      = (float*)alloc((size_t)N * OUT_C * 4);

  const int T = 256;
  const int G = (N + SCAN_CHUNK - 1) / SCAN_CHUNK;  // scan chunks (98)

  // CSR build
  k_zero_i32<<<(N + T - 1) / T, T, 0, stream>>>(counts, N);
  k_count<<<(E + T - 1) / T, T, 0, stream>>>(dst, counts, E);
  k_scan1<<<G, T, 0, stream>>>(counts, offsets, aux, N);
  k_scan2<<<1, T, 0, stream>>>(aux, auxs, G);
  k_scan3<<<(N + T - 1) / T, T, 0, stream>>>(offsets, auxs, cursor, N, E);
  k_dinv<<<(N + T - 1) / T, T, 0, stream>>>(counts, dinv, N);
  k_fill<<<(E + T - 1) / T, T, 0, stream>>>(src, dst, dinv, cursor, esrc, enorm, E);

  // layer 1
  k_gemm<IN_C, HID_C, false><<<(N + 63) / 64, T, 0, stream>>>(x, W1, h1, N);
  k_agg<HID_C><<<(N + 1) / 2, T, 0, stream>>>(h1, dinv, b1, offsets, esrc, enorm, ag1, N);

  // layer 2
  k_gemm<HID_C, OUT_C, true><<<(N + 63) / 64, T, 0, stream>>>(ag1, W2, h2, N);
  k_agg<OUT_C><<<(N + 3) / 4, T, 0, stream>>>(h2, dinv, b2, offsets, esrc, enorm, out, N);
}

// Round 3
// 254.131 us; speedup vs baseline: 6.9152x; 1.3390x over previous
//
#include <hip/hip_runtime.h>
#include <math.h>

// GCN 2-layer: out = Anorm( relu( Anorm(X W1) + b1 ) W2 ) + b2
// R3: bf16 MFMA GEMMs (16x16x32), fp32 accumulate. W pre-swizzled to
// frag-contiguous layout; A-frag fp32->bf16 convert fused into GEMM1 load.
// h1/ag1/h2 stored bf16 -> halves gather bytes in agg; relu+pack fused
// into agg1 epilogue. CSR build (histogram/scan/fill) unchanged from R2.

typedef __bf16 bf16x8 __attribute__((ext_vector_type(8)));
typedef float f32x4 __attribute__((ext_vector_type(4)));

union ABu {
  unsigned short u16[8];
  uint4 u4;
  bf16x8 v;
};

__device__ inline unsigned short f2bf(float f) {  // RNE
  unsigned u = __float_as_uint(f);
  return (unsigned short)((u + 0x7fffu + ((u >> 16) & 1u)) >> 16);
}

__device__ inline void unpack8(uint4 v, float* f) {
  f[0] = __uint_as_float(v.x << 16);
  f[1] = __uint_as_float(v.x & 0xffff0000u);
  f[2] = __uint_as_float(v.y << 16);
  f[3] = __uint_as_float(v.y & 0xffff0000u);
  f[4] = __uint_as_float(v.z << 16);
  f[5] = __uint_as_float(v.z & 0xffff0000u);
  f[6] = __uint_as_float(v.w << 16);
  f[7] = __uint_as_float(v.w & 0xffff0000u);
}

// ---------------- CSR build ----------------

__global__ void k_zero_i32(int* __restrict__ p, int n) {
  int i = blockIdx.x * blockDim.x + threadIdx.x;
  if (i < n) p[i] = 0;
}

__global__ void k_count(const int* __restrict__ dst, int* __restrict__ counts, int E) {
  int e = blockIdx.x * blockDim.x + threadIdx.x;
  if (e < E) atomicAdd(&counts[dst[e]], 1);
}

__global__ void k_dinv(const int* __restrict__ counts, float* __restrict__ dinv, int n) {
  int i = blockIdx.x * blockDim.x + threadIdx.x;
  if (i < n) dinv[i] = rsqrtf((float)(counts[i] + 1));
}

constexpr int SCAN_CHUNK = 1024;

__global__ __launch_bounds__(256) void k_scan1(const int* __restrict__ counts,
                                               int* __restrict__ offsets,
                                               int* __restrict__ aux, int n) {
  __shared__ int tsum[256];
  int tid = threadIdx.x;
  int base = blockIdx.x * SCAN_CHUNK + tid * 4;
  int v0 = (base + 0 < n) ? counts[base + 0] : 0;
  int v1 = (base + 1 < n) ? counts[base + 1] : 0;
  int v2 = (base + 2 < n) ? counts[base + 2] : 0;
  int v3 = (base + 3 < n) ? counts[base + 3] : 0;
  int s = v0 + v1 + v2 + v3;
  tsum[tid] = s;
  __syncthreads();
  for (int off = 1; off < 256; off <<= 1) {
    int t = (tid >= off) ? tsum[tid - off] : 0;
    __syncthreads();
    tsum[tid] += t;
    __syncthreads();
  }
  int excl = tsum[tid] - s;
  if (base + 0 < n) offsets[base + 0] = excl;
  if (base + 1 < n) offsets[base + 1] = excl + v0;
  if (base + 2 < n) offsets[base + 2] = excl + v0 + v1;
  if (base + 3 < n) offsets[base + 3] = excl + v0 + v1 + v2;
  if (tid == 255) aux[blockIdx.x] = tsum[255];
}

__global__ __launch_bounds__(256) void k_scan2(const int* __restrict__ aux,
                                               int* __restrict__ auxs, int G) {
  __shared__ int tsum[256];
  int tid = threadIdx.x;
  int v = (tid < G) ? aux[tid] : 0;
  tsum[tid] = v;
  __syncthreads();
  for (int off = 1; off < 256; off <<= 1) {
    int t = (tid >= off) ? tsum[tid - off] : 0;
    __syncthreads();
    tsum[tid] += t;
    __syncthreads();
  }
  if (tid < G) auxs[tid] = tsum[tid] - v;
}

__global__ void k_scan3(int* __restrict__ offsets, const int* __restrict__ auxs,
                        int* __restrict__ cursor, int n, int E) {
  int i = blockIdx.x * blockDim.x + threadIdx.x;
  if (i < n) {
    int v = offsets[i] + auxs[i / SCAN_CHUNK];
    offsets[i] = v;
    cursor[i] = v;
  }
  if (i == 0) offsets[n] = E;
}

// bucket fill: edata[pos] = {src, bitcast(norm)} sorted by dst
__global__ void k_fill(const int* __restrict__ src, const int* __restrict__ dst,
                       const float* __restrict__ dinv, int* __restrict__ cursor,
                       uint2* __restrict__ edata, int E) {
  int e = blockIdx.x * blockDim.x + threadIdx.x;
  if (e >= E) return;
  int s = src[e];
  int d = dst[e];
  int pos = atomicAdd(&cursor[d], 1);
  edata[pos] = make_uint2((unsigned)s, __float_as_uint(dinv[s] * dinv[d]));
}

// ---------------- W swizzle: Wb[((k>>3)*N + n)*8 + (k&7)] = bf16(W[k*N+n]) ----
__global__ void k_convW(const float* __restrict__ W, unsigned short* __restrict__ Wb,
                        int K, int N) {
  int idx = blockIdx.x * blockDim.x + threadIdx.x;
  if (idx >= K * N) return;
  int k = idx / N;
  int n = idx % N;
  Wb[((size_t)(k >> 3) * N + n) * 8 + (k & 7)] = f2bf(W[idx]);
}

// ---------------- MFMA GEMM: Cb[M,N](bf16) = A[M,K] @ W[K,N] ----------------
// A-frag layout: A[m=lane&15][k=(lane>>4)*8+j]; B from pre-swizzled Wb;
// C/D layout: col=lane&15, row=(lane>>4)*4+reg (m89/m91-verified).
template<int K, int N, bool A_F32>
__global__ __launch_bounds__(256) void k_gemm_mfma(const void* __restrict__ Ap,
                                                   const unsigned short* __restrict__ Wb,
                                                   unsigned short* __restrict__ Cb,
                                                   int M) {
  constexpr int NT = N / 16;
  constexpr int KS = K / 32;
  const int tid = threadIdx.x;
  const int wave = tid >> 6;
  const int lane = tid & 63;
  const int q = lane >> 4;
  const int l15 = lane & 15;
  const int row0 = blockIdx.x * 64 + wave * 16;
  const int rowA = row0 + l15;

  f32x4 zero = {0.0f, 0.0f, 0.0f, 0.0f};
  f32x4 acc[NT];
#pragma unroll
  for (int t = 0; t < NT; ++t) acc[t] = zero;

#pragma unroll
  for (int kk = 0; kk < KS; ++kk) {
    ABu a;
    if (A_F32) {
      float4 f0 = make_float4(0.f, 0.f, 0.f, 0.f);
      float4 f1 = make_float4(0.f, 0.f, 0.f, 0.f);
      if (rowA < M) {
        const float4* ap =
            (const float4*)((const float*)Ap + (size_t)rowA * K + kk * 32 + q * 8);
        f0 = ap[0];
        f1 = ap[1];
      }
      a.u16[0] = f2bf(f0.x); a.u16[1] = f2bf(f0.y);
      a.u16[2] = f2bf(f0.z); a.u16[3] = f2bf(f0.w);
      a.u16[4] = f2bf(f1.x); a.u16[5] = f2bf(f1.y);
      a.u16[6] = f2bf(f1.z); a.u16[7] = f2bf(f1.w);
    } else {
      uint4 raw = make_uint4(0, 0, 0, 0);
      if (rowA < M)
        raw = *(const uint4*)((const unsigned short*)Ap + (size_t)rowA * K +
                              kk * 32 + q * 8);
      a.u4 = raw;
    }
#pragma unroll
    for (int nt = 0; nt < NT; ++nt) {
      ABu b;
      b.u4 = *(const uint4*)(Wb + ((size_t)(kk * 4 + q) * N + nt * 16 + l15) * 8);
      acc[nt] = __builtin_amdgcn_mfma_f32_16x16x32_bf16(a.v, b.v, acc[nt], 0, 0, 0);
    }
  }

#pragma unroll
  for (int nt = 0; nt < NT; ++nt) {
#pragma unroll
    for (int v = 0; v < 4; ++v) {
      int row = row0 + q * 4 + v;
      if (row < M) Cb[(size_t)row * N + nt * 16 + l15] = f2bf(acc[nt][v]);
    }
  }
}

// ---------------- CSR gather aggregation (bf16 input) ----------------
// out[i,:] = h[i,:]*dinv[i]^2 + b + sum_{e in row i} h[esrc[e],:]*norm[e]
// OUT_BF16_RELU: out = bf16(relu(.)) ; else fp32.
template<int C, bool OUT_BF16_RELU>
__global__ __launch_bounds__(256) void k_agg(const unsigned short* __restrict__ hb,
                                             const float* __restrict__ dinv,
                                             const float* __restrict__ bias,
                                             const int* __restrict__ offsets,
                                             const uint2* __restrict__ edata,
                                             void* __restrict__ outp, int n) {
  constexpr int CQ = C / 8;  // lanes per node
  const int tid = threadIdx.x;
  const int node = blockIdx.x * (256 / CQ) + tid / CQ;
  const int q = tid % CQ;
  if (node >= n) return;

  const uint4* h4 = (const uint4*)hb;
  float di = dinv[node];
  float s2 = di * di;

  float hs[8];
  unpack8(h4[(size_t)node * CQ + q], hs);
  float acc[8];
#pragma unroll
  for (int i = 0; i < 8; ++i) acc[i] = fmaf(hs[i], s2, bias[q * 8 + i]);

  int e0 = offsets[node];
  int e1 = offsets[node + 1];
  for (int e = e0; e < e1; ++e) {
    uint2 ed = edata[e];
    float nrm = __uint_as_float(ed.y);
    float hv[8];
    unpack8(h4[(size_t)ed.x * CQ + q], hv);
#pragma unroll
    for (int i = 0; i < 8; ++i) acc[i] = fmaf(hv[i], nrm, acc[i]);
  }

  if (OUT_BF16_RELU) {
#pragma unroll
    for (int i = 0; i < 8; ++i) acc[i] = fmaxf(acc[i], 0.0f);
    uint4 o;
    o.x = (unsigned)f2bf(acc[0]) | ((unsigned)f2bf(acc[1]) << 16);
    o.y = (unsigned)f2bf(acc[2]) | ((unsigned)f2bf(acc[3]) << 16);
    o.z = (unsigned)f2bf(acc[4]) | ((unsigned)f2bf(acc[5]) << 16);
    o.w = (unsigned)f2bf(acc[6]) | ((unsigned)f2bf(acc[7]) << 16);
    ((uint4*)outp)[(size_t)node * CQ + q] = o;
  } else {
    float4 o0 = make_float4(acc[0], acc[1], acc[2], acc[3]);
    float4 o1 = make_float4(acc[4], acc[5], acc[6], acc[7]);
    ((float4*)outp)[(size_t)node * (C / 4) + q * 2 + 0] = o0;
    ((float4*)outp)[(size_t)node * (C / 4) + q * 2 + 1] = o1;
  }
}

// ---------------- launch ----------------

extern "C" void kernel_launch(void* const* d_in, const int* in_sizes, int n_in,
                              void* d_out, int out_size, void* d_ws, size_t ws_size,
                              hipStream_t stream) {
  const float* x  = (const float*)d_in[0];
  const float* W1 = (const float*)d_in[1];
  const float* b1 = (const float*)d_in[2];
  const float* W2 = (const float*)d_in[3];
  const float* b2 = (const float*)d_in[4];
  const int* src  = (const int*)d_in[5];
  const int* dst  = (const int*)d_in[6];
  float* out = (float*)d_out;

  constexpr int IN_C = 128, HID_C = 128, OUT_C = 64;
  const int N = in_sizes[0] / IN_C;   // 100000
  const int E = in_sizes[5];          // 600000

  char* p = (char*)d_ws;
  auto alloc = [&](size_t bytes) {
    char* r = p;
    p += (bytes + 255) & ~(size_t)255;
    return r;
  };
  float* dinv    = (float*)alloc((size_t)N * 4);
  int*   offsets = (int*)alloc((size_t)(N + 1) * 4);
  int*   counts  = (int*)alloc((size_t)N * 4);
  int*   cursor  = (int*)alloc((size_t)N * 4);
  int*   aux     = (int*)alloc(1024);
  int*   auxs    = (int*)alloc(1024);
  uint2* edata   = (uint2*)alloc((size_t)E * 8);
  unsigned short* Wb1 = (unsigned short*)alloc((size_t)IN_C * HID_C * 2);
  unsigned short* Wb2 = (unsigned short*)alloc((size_t)HID_C * OUT_C * 2);
  unsigned short* h1b = (unsigned short*)alloc((size_t)N * HID_C * 2);
  unsigned short* ag1 = (unsigned short*)alloc((size_t)N * HID_C * 2);
  unsigned short* h2b = (unsigned short*)alloc((size_t)N * OUT_C * 2);

  const int T = 256;
  const int G = (N + SCAN_CHUNK - 1) / SCAN_CHUNK;

  // CSR build + weight swizzle
  k_zero_i32<<<(N + T - 1) / T, T, 0, stream>>>(counts, N);
  k_count<<<(E + T - 1) / T, T, 0, stream>>>(dst, counts, E);
  k_scan1<<<G, T, 0, stream>>>(counts, offsets, aux, N);
  k_scan2<<<1, T, 0, stream>>>(aux, auxs, G);
  k_scan3<<<(N + T - 1) / T, T, 0, stream>>>(offsets, auxs, cursor, N, E);
  k_dinv<<<(N + T - 1) / T, T, 0, stream>>>(counts, dinv, N);
  k_fill<<<(E + T - 1) / T, T, 0, stream>>>(src, dst, dinv, cursor, edata, E);
  k_convW<<<(IN_C * HID_C + T - 1) / T, T, 0, stream>>>(W1, Wb1, IN_C, HID_C);
  k_convW<<<(HID_C * OUT_C + T - 1) / T, T, 0, stream>>>(W2, Wb2, HID_C, OUT_C);

  // layer 1: h1 = X @ W1 (bf16 out), ag1 = bf16(relu(Anorm h1 + b1))
  k_gemm_mfma<IN_C, HID_C, true><<<(N + 63) / 64, T, 0, stream>>>(x, Wb1, h1b, N);
  k_agg<HID_C, true><<<(N + 15) / 16, T, 0, stream>>>(h1b, dinv, b1, offsets, edata, ag1, N);

  // layer 2: h2 = ag1 @ W2 (bf16 out), out = Anorm h2 + b2 (fp32)
  k_gemm_mfma<HID_C, OUT_C, false><<<(N + 63) / 64, T, 0, stream>>>(ag1, Wb2, h2b, N);
  k_agg<OUT_C, false><<<(N + 31) / 32, T, 0, stream>>>(h2b, dinv, b2, offsets, edata, out, N);
}

// Round 4
// 239.668 us; speedup vs baseline: 7.3325x; 1.0603x over previous
//
#include <hip/hip_runtime.h>
#include <math.h>

// GCN 2-layer: out = Anorm( relu( Anorm(X W1) + b1 ) W2 ) + b2
// R4: (a) norm folded into GEMM epilogue (h stored pre-scaled by dinv[row])
//     -> k_fill scatters only esrc (4B, was 8B w/ dinv gathers);
//     (b) agg1+GEMM2 fused (LDS tile, no ag1 round trip);
//     (c) dinv fused into scan3, one convW kernel, agg loops unrolled x2.

typedef __bf16 bf16x8 __attribute__((ext_vector_type(8)));
typedef float f32x4 __attribute__((ext_vector_type(4)));

union ABu {
  unsigned short u16[8];
  uint4 u4;
  bf16x8 v;
};

__device__ inline unsigned short f2bf(float f) {  // RNE
  unsigned u = __float_as_uint(f);
  return (unsigned short)((u + 0x7fffu + ((u >> 16) & 1u)) >> 16);
}

__device__ inline void unpack8(uint4 v, float* f) {
  f[0] = __uint_as_float(v.x << 16);
  f[1] = __uint_as_float(v.x & 0xffff0000u);
  f[2] = __uint_as_float(v.y << 16);
  f[3] = __uint_as_float(v.y & 0xffff0000u);
  f[4] = __uint_as_float(v.z << 16);
  f[5] = __uint_as_float(v.z & 0xffff0000u);
  f[6] = __uint_as_float(v.w << 16);
  f[7] = __uint_as_float(v.w & 0xffff0000u);
}

__device__ inline uint4 pack8(const float* a) {
  uint4 o;
  o.x = (unsigned)f2bf(a[0]) | ((unsigned)f2bf(a[1]) << 16);
  o.y = (unsigned)f2bf(a[2]) | ((unsigned)f2bf(a[3]) << 16);
  o.z = (unsigned)f2bf(a[4]) | ((unsigned)f2bf(a[5]) << 16);
  o.w = (unsigned)f2bf(a[6]) | ((unsigned)f2bf(a[7]) << 16);
  return o;
}

// ---------------- CSR build ----------------

__global__ void k_zero_i32(int* __restrict__ p, int n) {
  int i = blockIdx.x * blockDim.x + threadIdx.x;
  if (i < n) p[i] = 0;
}

__global__ void k_count(const int* __restrict__ dst, int* __restrict__ counts, int E) {
  int e = blockIdx.x * blockDim.x + threadIdx.x;
  if (e < E) atomicAdd(&counts[dst[e]], 1);
}

constexpr int SCAN_CHUNK = 1024;

__global__ __launch_bounds__(256) void k_scan1(const int* __restrict__ counts,
                                               int* __restrict__ offsets,
                                               int* __restrict__ aux, int n) {
  __shared__ int tsum[256];
  int tid = threadIdx.x;
  int base = blockIdx.x * SCAN_CHUNK + tid * 4;
  int v0 = (base + 0 < n) ? counts[base + 0] : 0;
  int v1 = (base + 1 < n) ? counts[base + 1] : 0;
  int v2 = (base + 2 < n) ? counts[base + 2] : 0;
  int v3 = (base + 3 < n) ? counts[base + 3] : 0;
  int s = v0 + v1 + v2 + v3;
  tsum[tid] = s;
  __syncthreads();
  for (int off = 1; off < 256; off <<= 1) {
    int t = (tid >= off) ? tsum[tid - off] : 0;
    __syncthreads();
    tsum[tid] += t;
    __syncthreads();
  }
  int excl = tsum[tid] - s;
  if (base + 0 < n) offsets[base + 0] = excl;
  if (base + 1 < n) offsets[base + 1] = excl + v0;
  if (base + 2 < n) offsets[base + 2] = excl + v0 + v1;
  if (base + 3 < n) offsets[base + 3] = excl + v0 + v1 + v2;
  if (tid == 255) aux[blockIdx.x] = tsum[255];
}

__global__ __launch_bounds__(256) void k_scan2(const int* __restrict__ aux,
                                               int* __restrict__ auxs, int G) {
  __shared__ int tsum[256];
  int tid = threadIdx.x;
  int v = (tid < G) ? aux[tid] : 0;
  tsum[tid] = v;
  __syncthreads();
  for (int off = 1; off < 256; off <<= 1) {
    int t = (tid >= off) ? tsum[tid - off] : 0;
    __syncthreads();
    tsum[tid] += t;
    __syncthreads();
  }
  if (tid < G) auxs[tid] = tsum[tid] - v;
}

// offsets += chunk base; cursor = copy; dinv = rsqrt(counts+1); offsets[n]=E
__global__ void k_scan3_dinv(int* __restrict__ offsets, const int* __restrict__ auxs,
                             int* __restrict__ cursor, const int* __restrict__ counts,
                             float* __restrict__ dinv, int n, int E) {
  int i = blockIdx.x * blockDim.x + threadIdx.x;
  if (i < n) {
    int v = offsets[i] + auxs[i / SCAN_CHUNK];
    offsets[i] = v;
    cursor[i] = v;
    dinv[i] = rsqrtf((float)(counts[i] + 1));
  }
  if (i == 0) offsets[n] = E;
}

// bucket fill: esrc sorted by dst (4B scatter only)
__global__ void k_fill(const int* __restrict__ src, const int* __restrict__ dst,
                       int* __restrict__ cursor, int* __restrict__ esrc, int E) {
  int e = blockIdx.x * blockDim.x + threadIdx.x;
  if (e >= E) return;
  int s = src[e];
  int d = dst[e];
  int pos = atomicAdd(&cursor[d], 1);
  esrc[pos] = s;
}

// ---------------- weight swizzle (both) ----------------
// Wb[((k>>3)*N + n)*8 + (k&7)] = bf16(W[k*N+n])
__global__ void k_convW(const float* __restrict__ W1, const float* __restrict__ W2,
                        unsigned short* __restrict__ Wb1,
                        unsigned short* __restrict__ Wb2) {
  int idx = blockIdx.x * blockDim.x + threadIdx.x;
  if (idx < 128 * 128) {
    int k = idx >> 7, n = idx & 127;
    Wb1[(((k >> 3) << 7) + n) * 8 + (k & 7)] = f2bf(W1[idx]);
  } else if (idx < 128 * 128 + 128 * 64) {
    int j = idx - 128 * 128;
    int k = j >> 6, n = j & 63;
    Wb2[(((k >> 3) << 6) + n) * 8 + (k & 7)] = f2bf(W2[j]);
  }
}

// ---------------- GEMM1: h1s[M,128](bf16) = (X[M,128] @ W1) * dinv[row] -----
// A-frag: A[m=lane&15][k=(lane>>4)*8+j]; C/D: col=lane&15, row=(lane>>4)*4+reg
__global__ __launch_bounds__(256) void k_gemm1(const float* __restrict__ X,
                                               const unsigned short* __restrict__ Wb,
                                               const float* __restrict__ dinv,
                                               unsigned short* __restrict__ Cb, int M) {
  constexpr int K = 128, N = 128, NT = N / 16, KS = K / 32;
  const int tid = threadIdx.x;
  const int wave = tid >> 6;
  const int lane = tid & 63;
  const int q = lane >> 4;
  const int l15 = lane & 15;
  const int row0 = blockIdx.x * 64 + wave * 16;
  const int rowA = row0 + l15;

  f32x4 zero = {0.0f, 0.0f, 0.0f, 0.0f};
  f32x4 acc[NT];
#pragma unroll
  for (int t = 0; t < NT; ++t) acc[t] = zero;

#pragma unroll
  for (int kk = 0; kk < KS; ++kk) {
    ABu a;
    float4 f0 = make_float4(0.f, 0.f, 0.f, 0.f);
    float4 f1 = make_float4(0.f, 0.f, 0.f, 0.f);
    if (rowA < M) {
      const float4* ap = (const float4*)(X + (size_t)rowA * K + kk * 32 + q * 8);
      f0 = ap[0];
      f1 = ap[1];
    }
    a.u16[0] = f2bf(f0.x); a.u16[1] = f2bf(f0.y);
    a.u16[2] = f2bf(f0.z); a.u16[3] = f2bf(f0.w);
    a.u16[4] = f2bf(f1.x); a.u16[5] = f2bf(f1.y);
    a.u16[6] = f2bf(f1.z); a.u16[7] = f2bf(f1.w);
#pragma unroll
    for (int nt = 0; nt < NT; ++nt) {
      ABu b;
      b.u4 = *(const uint4*)(Wb + ((size_t)(kk * 4 + q) * N + nt * 16 + l15) * 8);
      acc[nt] = __builtin_amdgcn_mfma_f32_16x16x32_bf16(a.v, b.v, acc[nt], 0, 0, 0);
    }
  }

#pragma unroll
  for (int v = 0; v < 4; ++v) {
    int row = row0 + q * 4 + v;
    if (row < M) {
      float di = dinv[row];
#pragma unroll
      for (int nt = 0; nt < NT; ++nt)
        Cb[(size_t)row * N + nt * 16 + l15] = f2bf(acc[nt][v] * di);
    }
  }
}

// ---------------- fused agg1 + GEMM2 ----------------
// Phase 1: ag[nl,:] = bf16(relu(dinv[node]*(h1s[node]+sum h1s[esrc]) + b1)) -> LDS
// Phase 2: h2s[16,64] = (ag @ W2) * dinv[row]   (bf16 out)
__global__ __launch_bounds__(256) void k_aggemm(const unsigned short* __restrict__ h1s,
                                                const float* __restrict__ dinv,
                                                const float* __restrict__ b1,
                                                const int* __restrict__ offsets,
                                                const int* __restrict__ esrc,
                                                const unsigned short* __restrict__ Wb2,
                                                unsigned short* __restrict__ h2s,
                                                int n) {
  constexpr int LDA = 136;  // 128 + 8 pad (bank-conflict break), 16B-aligned rows
  __shared__ unsigned short As[16 * LDA];
  __shared__ float sdinv[16];
  const int tid = threadIdx.x;

  // phase 1: 16 nodes, 16 lanes each (8 ch/lane)
  {
    const int nl = tid >> 4;
    const int q = tid & 15;
    const int node = blockIdx.x * 16 + nl;
    float acc[8];
    if (node < n) {
      const uint4* h4 = (const uint4*)h1s;
      float di = dinv[node];
      if (q == 0) sdinv[nl] = di;
      float hs[8];
      unpack8(h4[(size_t)node * 16 + q], hs);
#pragma unroll
      for (int i = 0; i < 8; ++i) acc[i] = hs[i];  // self (h1s pre-scaled)
      int e0 = offsets[node];
      int e1 = offsets[node + 1];
      int e = e0;
      for (; e + 1 < e1; e += 2) {
        int s0 = esrc[e];
        int s1 = esrc[e + 1];
        uint4 r0 = h4[(size_t)s0 * 16 + q];
        uint4 r1 = h4[(size_t)s1 * 16 + q];
        float h0[8], h1v[8];
        unpack8(r0, h0);
        unpack8(r1, h1v);
#pragma unroll
        for (int i = 0; i < 8; ++i) acc[i] += h0[i] + h1v[i];
      }
      if (e < e1) {
        float hv[8];
        unpack8(h4[(size_t)esrc[e] * 16 + q], hv);
#pragma unroll
        for (int i = 0; i < 8; ++i) acc[i] += hv[i];
      }
      const float4* b14 = (const float4*)b1;
      float4 ba = b14[q * 2], bb = b14[q * 2 + 1];
      float bias[8] = {ba.x, ba.y, ba.z, ba.w, bb.x, bb.y, bb.z, bb.w};
#pragma unroll
      for (int i = 0; i < 8; ++i) acc[i] = fmaxf(fmaf(acc[i], di, bias[i]), 0.f);
    } else {
      if (q == 0) sdinv[nl] = 0.f;
#pragma unroll
      for (int i = 0; i < 8; ++i) acc[i] = 0.f;
    }
    *(uint4*)&As[nl * LDA + q * 8] = pack8(acc);
  }
  __syncthreads();

  // phase 2: one wave per 16-col tile; 4 MFMAs each
  {
    const int wave = tid >> 6;
    const int lane = tid & 63;
    const int q = lane >> 4;
    const int l15 = lane & 15;
    f32x4 acc = {0.0f, 0.0f, 0.0f, 0.0f};
#pragma unroll
    for (int kk = 0; kk < 4; ++kk) {
      ABu a, b;
      a.u4 = *(const uint4*)&As[l15 * LDA + kk * 32 + q * 8];
      b.u4 = *(const uint4*)(Wb2 + ((size_t)(kk * 4 + q) * 64 + wave * 16 + l15) * 8);
      acc = __builtin_amdgcn_mfma_f32_16x16x32_bf16(a.v, b.v, acc, 0, 0, 0);
    }
#pragma unroll
    for (int v = 0; v < 4; ++v) {
      int rl = q * 4 + v;
      int row = blockIdx.x * 16 + rl;
      if (row < n) h2s[(size_t)row * 64 + wave * 16 + l15] = f2bf(acc[v] * sdinv[rl]);
    }
  }
}

// ---------------- agg2: out[node,:] = dinv*(h2s[node]+sum h2s[esrc]) + b2 ----
__global__ __launch_bounds__(256) void k_agg2(const unsigned short* __restrict__ h2s,
                                              const float* __restrict__ dinv,
                                              const float* __restrict__ b2,
                                              const int* __restrict__ offsets,
                                              const int* __restrict__ esrc,
                                              float* __restrict__ out, int n) {
  constexpr int CQ = 8;  // 64 ch / 8 per lane
  const int tid = threadIdx.x;
  const int node = blockIdx.x * 32 + tid / CQ;
  const int q = tid % CQ;
  if (node >= n) return;

  const uint4* h4 = (const uint4*)h2s;
  float di = dinv[node];
  float acc[8];
  unpack8(h4[(size_t)node * CQ + q], acc);

  int e0 = offsets[node];
  int e1 = offsets[node + 1];
  int e = e0;
  for (; e + 1 < e1; e += 2) {
    int s0 = esrc[e];
    int s1 = esrc[e + 1];
    uint4 r0 = h4[(size_t)s0 * CQ + q];
    uint4 r1 = h4[(size_t)s1 * CQ + q];
    float h0[8], h1v[8];
    unpack8(r0, h0);
    unpack8(r1, h1v);
#pragma unroll
    for (int i = 0; i < 8; ++i) acc[i] += h0[i] + h1v[i];
  }
  if (e < e1) {
    float hv[8];
    unpack8(h4[(size_t)esrc[e] * CQ + q], hv);
#pragma unroll
    for (int i = 0; i < 8; ++i) acc[i] += hv[i];
  }

  const float4* b24 = (const float4*)b2;
  float4 ba = b24[q * 2], bb = b24[q * 2 + 1];
  float bias[8] = {ba.x, ba.y, ba.z, ba.w, bb.x, bb.y, bb.z, bb.w};
  float4 o0, o1;
  o0.x = fmaf(acc[0], di, bias[0]);
  o0.y = fmaf(acc[1], di, bias[1]);
  o0.z = fmaf(acc[2], di, bias[2]);
  o0.w = fmaf(acc[3], di, bias[3]);
  o1.x = fmaf(acc[4], di, bias[4]);
  o1.y = fmaf(acc[5], di, bias[5]);
  o1.z = fmaf(acc[6], di, bias[6]);
  o1.w = fmaf(acc[7], di, bias[7]);
  ((float4*)out)[(size_t)node * 16 + q * 2 + 0] = o0;
  ((float4*)out)[(size_t)node * 16 + q * 2 + 1] = o1;
}

// ---------------- launch ----------------

extern "C" void kernel_launch(void* const* d_in, const int* in_sizes, int n_in,
                              void* d_out, int out_size, void* d_ws, size_t ws_size,
                              hipStream_t stream) {
  const float* x  = (const float*)d_in[0];
  const float* W1 = (const float*)d_in[1];
  const float* b1 = (const float*)d_in[2];
  const float* W2 = (const float*)d_in[3];
  const float* b2 = (const float*)d_in[4];
  const int* src  = (const int*)d_in[5];
  const int* dst  = (const int*)d_in[6];
  float* out = (float*)d_out;

  constexpr int IN_C = 128, HID_C = 128, OUT_C = 64;
  const int N = in_sizes[0] / IN_C;   // 100000
  const int E = in_sizes[5];          // 600000

  char* p = (char*)d_ws;
  auto alloc = [&](size_t bytes) {
    char* r = p;
    p += (bytes + 255) & ~(size_t)255;
    return r;
  };
  float* dinv    = (float*)alloc((size_t)N * 4);
  int*   offsets = (int*)alloc((size_t)(N + 1) * 4);
  int*   counts  = (int*)alloc((size_t)N * 4);
  int*   cursor  = (int*)alloc((size_t)N * 4);
  int*   aux     = (int*)alloc(1024);
  int*   auxs    = (int*)alloc(1024);
  int*   esrc    = (int*)alloc((size_t)E * 4);
  unsigned short* Wb1 = (unsigned short*)alloc((size_t)IN_C * HID_C * 2);
  unsigned short* Wb2 = (unsigned short*)alloc((size_t)HID_C * OUT_C * 2);
  unsigned short* h1s = (unsigned short*)alloc((size_t)N * HID_C * 2);
  unsigned short* h2s = (unsigned short*)alloc((size_t)N * OUT_C * 2);

  const int T = 256;
  const int G = (N + SCAN_CHUNK - 1) / SCAN_CHUNK;

  k_zero_i32<<<(N + T - 1) / T, T, 0, stream>>>(counts, N);
  k_count<<<(E + T - 1) / T, T, 0, stream>>>(dst, counts, E);
  k_scan1<<<G, T, 0, stream>>>(counts, offsets, aux, N);
  k_scan2<<<1, T, 0, stream>>>(aux, auxs, G);
  k_scan3_dinv<<<(N + T - 1) / T, T, 0, stream>>>(offsets, auxs, cursor, counts, dinv, N, E);
  k_fill<<<(E + T - 1) / T, T, 0, stream>>>(src, dst, cursor, esrc, E);
  k_convW<<<(IN_C * HID_C + HID_C * OUT_C + T - 1) / T, T, 0, stream>>>(W1, W2, Wb1, Wb2);

  k_gemm1<<<(N + 63) / 64, T, 0, stream>>>(x, Wb1, dinv, h1s, N);
  k_aggemm<<<(N + 15) / 16, T, 0, stream>>>(h1s, dinv, b1, offsets, esrc, Wb2, h2s, N);
  k_agg2<<<(N + 31) / 32, T, 0, stream>>>(h2s, dinv, b2, offsets, esrc, out, N);
}

// Round 5
// 229.977 us; speedup vs baseline: 7.6415x; 1.0421x over previous
//
#include <hip/hip_runtime.h>
#include <math.h>

// GCN 2-layer: out = Anorm( relu( Anorm(X W1) + b1 ) W2 ) + b2
// R5: (a) fill+gemm1 co-scheduled in one dispatch (independent work, fill is
//     atomic-latency-bound, gemm1 MFMA/HBM-bound); (b) count+convW merged;
//     (c) scan2 folded into scan3 (per-block redundant aux scan);
//     (d) gather loops unrolled x4 for L3 latency hiding. 7 dispatches.

typedef __bf16 bf16x8 __attribute__((ext_vector_type(8)));
typedef float f32x4 __attribute__((ext_vector_type(4)));

union ABu {
  unsigned short u16[8];
  uint4 u4;
  bf16x8 v;
};

__device__ inline unsigned short f2bf(float f) {  // RNE
  unsigned u = __float_as_uint(f);
  return (unsigned short)((u + 0x7fffu + ((u >> 16) & 1u)) >> 16);
}

__device__ inline void unpack8(uint4 v, float* f) {
  f[0] = __uint_as_float(v.x << 16);
  f[1] = __uint_as_float(v.x & 0xffff0000u);
  f[2] = __uint_as_float(v.y << 16);
  f[3] = __uint_as_float(v.y & 0xffff0000u);
  f[4] = __uint_as_float(v.z << 16);
  f[5] = __uint_as_float(v.z & 0xffff0000u);
  f[6] = __uint_as_float(v.w << 16);
  f[7] = __uint_as_float(v.w & 0xffff0000u);
}

__device__ inline uint4 pack8(const float* a) {
  uint4 o;
  o.x = (unsigned)f2bf(a[0]) | ((unsigned)f2bf(a[1]) << 16);
  o.y = (unsigned)f2bf(a[2]) | ((unsigned)f2bf(a[3]) << 16);
  o.z = (unsigned)f2bf(a[4]) | ((unsigned)f2bf(a[5]) << 16);
  o.w = (unsigned)f2bf(a[6]) | ((unsigned)f2bf(a[7]) << 16);
  return o;
}

constexpr int SCAN_CHUNK = 1024;

// ---------------- 1: zero counts ----------------
__global__ void k_zero_i32(int* __restrict__ p, int n) {
  int i = blockIdx.x * blockDim.x + threadIdx.x;
  if (i < n) p[i] = 0;
}

// ---------------- 2: count ∪ convW ----------------
// blocks [0,96): weight swizzle Wb[((k>>3)*N + n)*8 + (k&7)] = bf16(W[k*N+n])
// blocks [96,..): histogram of dst
__global__ __launch_bounds__(256) void k_count_convW(const int* __restrict__ dst,
                                                     int* __restrict__ counts,
                                                     const float* __restrict__ W1,
                                                     const float* __restrict__ W2,
                                                     unsigned short* __restrict__ Wb1,
                                                     unsigned short* __restrict__ Wb2,
                                                     int E) {
  constexpr int CONV_BLOCKS = (128 * 128 + 128 * 64) / 256;  // 96
  if (blockIdx.x < CONV_BLOCKS) {
    int idx = blockIdx.x * 256 + threadIdx.x;
    if (idx < 128 * 128) {
      int k = idx >> 7, n = idx & 127;
      Wb1[(((k >> 3) << 7) + n) * 8 + (k & 7)] = f2bf(W1[idx]);
    } else {
      int j = idx - 128 * 128;
      int k = j >> 6, n = j & 63;
      Wb2[(((k >> 3) << 6) + n) * 8 + (k & 7)] = f2bf(W2[j]);
    }
    return;
  }
  int e = (blockIdx.x - CONV_BLOCKS) * 256 + threadIdx.x;
  if (e < E) atomicAdd(&counts[dst[e]], 1);
}

// ---------------- 3: per-chunk scan ----------------
__global__ __launch_bounds__(256) void k_scan1(const int* __restrict__ counts,
                                               int* __restrict__ offsets,
                                               int* __restrict__ aux, int n) {
  __shared__ int tsum[256];
  int tid = threadIdx.x;
  int base = blockIdx.x * SCAN_CHUNK + tid * 4;
  int v0 = (base + 0 < n) ? counts[base + 0] : 0;
  int v1 = (base + 1 < n) ? counts[base + 1] : 0;
  int v2 = (base + 2 < n) ? counts[base + 2] : 0;
  int v3 = (base + 3 < n) ? counts[base + 3] : 0;
  int s = v0 + v1 + v2 + v3;
  tsum[tid] = s;
  __syncthreads();
  for (int off = 1; off < 256; off <<= 1) {
    int t = (tid >= off) ? tsum[tid - off] : 0;
    __syncthreads();
    tsum[tid] += t;
    __syncthreads();
  }
  int excl = tsum[tid] - s;
  if (base + 0 < n) offsets[base + 0] = excl;
  if (base + 1 < n) offsets[base + 1] = excl + v0;
  if (base + 2 < n) offsets[base + 2] = excl + v0 + v1;
  if (base + 3 < n) offsets[base + 3] = excl + v0 + v1 + v2;
  if (tid == 255) aux[blockIdx.x] = tsum[255];
}

// ---------------- 4: aux-scan (redundant per block) + offsets fixup + dinv ----
// Each block of 256 nodes lies within one 1024-chunk (256 | 1024), so a single
// LDS-scanned aux value per block range is indexed per node. G <= 256.
__global__ __launch_bounds__(256) void k_scan3_dinv(int* __restrict__ offsets,
                                                    const int* __restrict__ aux,
                                                    int* __restrict__ cursor,
                                                    const int* __restrict__ counts,
                                                    float* __restrict__ dinv,
                                                    int n, int E, int G) {
  __shared__ int saux[256];
  int tid = threadIdx.x;
  int v = (tid < G) ? aux[tid] : 0;
  saux[tid] = v;
  __syncthreads();
  for (int off = 1; off < 256; off <<= 1) {
    int t = (tid >= off) ? saux[tid - off] : 0;
    __syncthreads();
    saux[tid] += t;
    __syncthreads();
  }
  int excl = saux[tid] - v;
  __syncthreads();
  saux[tid] = excl;
  __syncthreads();

  int i = blockIdx.x * 256 + tid;
  if (i < n) {
    int o = offsets[i] + saux[i >> 10];
    offsets[i] = o;
    cursor[i] = o;
    dinv[i] = rsqrtf((float)(counts[i] + 1));
  }
  if (i == 0) offsets[n] = E;
}

// ---------------- 5: fill ∪ gemm1 ----------------
// blocks [0,FB): bucket fill (esrc sorted by dst, 4B scatter)
// blocks [FB,..): h1s[M,128](bf16) = (X[M,128] @ W1) * dinv[row]
// A-frag: A[m=lane&15][k=(lane>>4)*8+j]; C/D: col=lane&15, row=(lane>>4)*4+reg
__global__ __launch_bounds__(256) void k_fill_gemm1(const int* __restrict__ src,
                                                    const int* __restrict__ dst,
                                                    int* __restrict__ cursor,
                                                    int* __restrict__ esrc, int E, int FB,
                                                    const float* __restrict__ X,
                                                    const unsigned short* __restrict__ Wb,
                                                    const float* __restrict__ dinv,
                                                    unsigned short* __restrict__ Cb,
                                                    int M) {
  if (blockIdx.x < FB) {
    int e = blockIdx.x * 256 + threadIdx.x;
    if (e < E) {
      int s = src[e];
      int d = dst[e];
      int pos = atomicAdd(&cursor[d], 1);
      esrc[pos] = s;
    }
    return;
  }

  constexpr int K = 128, N = 128, NT = N / 16, KS = K / 32;
  const int bid = blockIdx.x - FB;
  const int tid = threadIdx.x;
  const int wave = tid >> 6;
  const int lane = tid & 63;
  const int q = lane >> 4;
  const int l15 = lane & 15;
  const int row0 = bid * 64 + wave * 16;
  const int rowA = row0 + l15;

  f32x4 zero = {0.0f, 0.0f, 0.0f, 0.0f};
  f32x4 acc[NT];
#pragma unroll
  for (int t = 0; t < NT; ++t) acc[t] = zero;

#pragma unroll
  for (int kk = 0; kk < KS; ++kk) {
    ABu a;
    float4 f0 = make_float4(0.f, 0.f, 0.f, 0.f);
    float4 f1 = make_float4(0.f, 0.f, 0.f, 0.f);
    if (rowA < M) {
      const float4* ap = (const float4*)(X + (size_t)rowA * K + kk * 32 + q * 8);
      f0 = ap[0];
      f1 = ap[1];
    }
    a.u16[0] = f2bf(f0.x); a.u16[1] = f2bf(f0.y);
    a.u16[2] = f2bf(f0.z); a.u16[3] = f2bf(f0.w);
    a.u16[4] = f2bf(f1.x); a.u16[5] = f2bf(f1.y);
    a.u16[6] = f2bf(f1.z); a.u16[7] = f2bf(f1.w);
#pragma unroll
    for (int nt = 0; nt < NT; ++nt) {
      ABu b;
      b.u4 = *(const uint4*)(Wb + ((size_t)(kk * 4 + q) * N + nt * 16 + l15) * 8);
      acc[nt] = __builtin_amdgcn_mfma_f32_16x16x32_bf16(a.v, b.v, acc[nt], 0, 0, 0);
    }
  }

#pragma unroll
  for (int v = 0; v < 4; ++v) {
    int row = row0 + q * 4 + v;
    if (row < M) {
      float di = dinv[row];
#pragma unroll
      for (int nt = 0; nt < NT; ++nt)
        Cb[(size_t)row * N + nt * 16 + l15] = f2bf(acc[nt][v] * di);
    }
  }
}

// ---------------- 6: fused agg1 + GEMM2 ----------------
// Phase 1: ag[nl,:] = bf16(relu(dinv[node]*(h1s[node]+sum h1s[esrc]) + b1)) -> LDS
// Phase 2: h2s[16,64] = (ag @ W2) * dinv[row]   (bf16 out)
__global__ __launch_bounds__(256) void k_aggemm(const unsigned short* __restrict__ h1s,
                                                const float* __restrict__ dinv,
                                                const float* __restrict__ b1,
                                                const int* __restrict__ offsets,
                                                const int* __restrict__ esrc,
                                                const unsigned short* __restrict__ Wb2,
                                                unsigned short* __restrict__ h2s,
                                                int n) {
  constexpr int LDA = 136;  // 128 + 8 pad, rows 16B-aligned
  __shared__ unsigned short As[16 * LDA];
  __shared__ float sdinv[16];
  const int tid = threadIdx.x;

  // phase 1: 16 nodes, 16 lanes each (8 ch/lane), gather unrolled x4
  {
    const int nl = tid >> 4;
    const int q = tid & 15;
    const int node = blockIdx.x * 16 + nl;
    float acc[8];
    if (node < n) {
      const uint4* h4 = (const uint4*)h1s;
      float di = dinv[node];
      if (q == 0) sdinv[nl] = di;
      unpack8(h4[(size_t)node * 16 + q], acc);  // self (pre-scaled)
      int e0 = offsets[node];
      int e1 = offsets[node + 1];
      int e = e0;
      for (; e + 3 < e1; e += 4) {
        int s0 = esrc[e + 0];
        int s1 = esrc[e + 1];
        int s2 = esrc[e + 2];
        int s3 = esrc[e + 3];
        uint4 r0 = h4[(size_t)s0 * 16 + q];
        uint4 r1 = h4[(size_t)s1 * 16 + q];
        uint4 r2 = h4[(size_t)s2 * 16 + q];
        uint4 r3 = h4[(size_t)s3 * 16 + q];
        float g0[8], g1[8], g2[8], g3[8];
        unpack8(r0, g0);
        unpack8(r1, g1);
        unpack8(r2, g2);
        unpack8(r3, g3);
#pragma unroll
        for (int i = 0; i < 8; ++i) acc[i] += (g0[i] + g1[i]) + (g2[i] + g3[i]);
      }
      for (; e < e1; ++e) {
        float gv[8];
        unpack8(h4[(size_t)esrc[e] * 16 + q], gv);
#pragma unroll
        for (int i = 0; i < 8; ++i) acc[i] += gv[i];
      }
      const float4* b14 = (const float4*)b1;
      float4 ba = b14[q * 2], bb = b14[q * 2 + 1];
      float bias[8] = {ba.x, ba.y, ba.z, ba.w, bb.x, bb.y, bb.z, bb.w};
#pragma unroll
      for (int i = 0; i < 8; ++i) acc[i] = fmaxf(fmaf(acc[i], di, bias[i]), 0.f);
    } else {
      if (q == 0) sdinv[nl] = 0.f;
#pragma unroll
      for (int i = 0; i < 8; ++i) acc[i] = 0.f;
    }
    *(uint4*)&As[nl * LDA + q * 8] = pack8(acc);
  }
  __syncthreads();

  // phase 2: one wave per 16-col tile; 4 MFMAs each
  {
    const int wave = tid >> 6;
    const int lane = tid & 63;
    const int q = lane >> 4;
    const int l15 = lane & 15;
    f32x4 acc = {0.0f, 0.0f, 0.0f, 0.0f};
#pragma unroll
    for (int kk = 0; kk < 4; ++kk) {
      ABu a, b;
      a.u4 = *(const uint4*)&As[l15 * LDA + kk * 32 + q * 8];
      b.u4 = *(const uint4*)(Wb2 + ((size_t)(kk * 4 + q) * 64 + wave * 16 + l15) * 8);
      acc = __builtin_amdgcn_mfma_f32_16x16x32_bf16(a.v, b.v, acc, 0, 0, 0);
    }
#pragma unroll
    for (int v = 0; v < 4; ++v) {
      int rl = q * 4 + v;
      int row = blockIdx.x * 16 + rl;
      if (row < n) h2s[(size_t)row * 64 + wave * 16 + l15] = f2bf(acc[v] * sdinv[rl]);
    }
  }
}

// ---------------- 7: agg2 ----------------
// out[node,:] = dinv*(h2s[node]+sum h2s[esrc]) + b2 (fp32 out)
__global__ __launch_bounds__(256) void k_agg2(const unsigned short* __restrict__ h2s,
                                              const float* __restrict__ dinv,
                                              const float* __restrict__ b2,
                                              const int* __restrict__ offsets,
                                              const int* __restrict__ esrc,
                                              float* __restrict__ out, int n) {
  constexpr int CQ = 8;  // 64 ch / 8 per lane
  const int tid = threadIdx.x;
  const int node = blockIdx.x * 32 + tid / CQ;
  const int q = tid % CQ;
  if (node >= n) return;

  const uint4* h4 = (const uint4*)h2s;
  float di = dinv[node];
  float acc[8];
  unpack8(h4[(size_t)node * CQ + q], acc);

  int e0 = offsets[node];
  int e1 = offsets[node + 1];
  int e = e0;
  for (; e + 3 < e1; e += 4) {
    int s0 = esrc[e + 0];
    int s1 = esrc[e + 1];
    int s2 = esrc[e + 2];
    int s3 = esrc[e + 3];
    uint4 r0 = h4[(size_t)s0 * CQ + q];
    uint4 r1 = h4[(size_t)s1 * CQ + q];
    uint4 r2 = h4[(size_t)s2 * CQ + q];
    uint4 r3 = h4[(size_t)s3 * CQ + q];
    float g0[8], g1[8], g2[8], g3[8];
    unpack8(r0, g0);
    unpack8(r1, g1);
    unpack8(r2, g2);
    unpack8(r3, g3);
#pragma unroll
    for (int i = 0; i < 8; ++i) acc[i] += (g0[i] + g1[i]) + (g2[i] + g3[i]);
  }
  for (; e < e1; ++e) {
    float gv[8];
    unpack8(h4[(size_t)esrc[e] * CQ + q], gv);
#pragma unroll
    for (int i = 0; i < 8; ++i) acc[i] += gv[i];
  }

  const float4* b24 = (const float4*)b2;
  float4 ba = b24[q * 2], bb = b24[q * 2 + 1];
  float bias[8] = {ba.x, ba.y, ba.z, ba.w, bb.x, bb.y, bb.z, bb.w};
  float4 o0, o1;
  o0.x = fmaf(acc[0], di, bias[0]);
  o0.y = fmaf(acc[1], di, bias[1]);
  o0.z = fmaf(acc[2], di, bias[2]);
  o0.w = fmaf(acc[3], di, bias[3]);
  o1.x = fmaf(acc[4], di, bias[4]);
  o1.y = fmaf(acc[5], di, bias[5]);
  o1.z = fmaf(acc[6], di, bias[6]);
  o1.w = fmaf(acc[7], di, bias[7]);
  ((float4*)out)[(size_t)node * 16 + q * 2 + 0] = o0;
  ((float4*)out)[(size_t)node * 16 + q * 2 + 1] = o1;
}

// ---------------- launch ----------------

extern "C" void kernel_launch(void* const* d_in, const int* in_sizes, int n_in,
                              void* d_out, int out_size, void* d_ws, size_t ws_size,
                              hipStream_t stream) {
  const float* x  = (const float*)d_in[0];
  const float* W1 = (const float*)d_in[1];
  const float* b1 = (const float*)d_in[2];
  const float* W2 = (const float*)d_in[3];
  const float* b2 = (const float*)d_in[4];
  const int* src  = (const int*)d_in[5];
  const int* dst  = (const int*)d_in[6];
  float* out = (float*)d_out;

  constexpr int IN_C = 128, HID_C = 128, OUT_C = 64;
  const int N = in_sizes[0] / IN_C;   // 100000
  const int E = in_sizes[5];          // 600000

  char* p = (char*)d_ws;
  auto alloc = [&](size_t bytes) {
    char* r = p;
    p += (bytes + 255) & ~(size_t)255;
    return r;
  };
  float* dinv    = (float*)alloc((size_t)N * 4);
  int*   offsets = (int*)alloc((size_t)(N + 1) * 4);
  int*   counts  = (int*)alloc((size_t)N * 4);
  int*   cursor  = (int*)alloc((size_t)N * 4);
  int*   aux     = (int*)alloc(1024);
  int*   esrc    = (int*)alloc((size_t)E * 4);
  unsigned short* Wb1 = (unsigned short*)alloc((size_t)IN_C * HID_C * 2);
  unsigned short* Wb2 = (unsigned short*)alloc((size_t)HID_C * OUT_C * 2);
  unsigned short* h1s = (unsigned short*)alloc((size_t)N * HID_C * 2);
  unsigned short* h2s = (unsigned short*)alloc((size_t)N * OUT_C * 2);

  const int T = 256;
  const int G = (N + SCAN_CHUNK - 1) / SCAN_CHUNK;  // 98 (must be <= 256)
  const int FB = (E + T - 1) / T;                   // fill blocks
  const int GB = (N + 63) / 64;                     // gemm1 blocks
  constexpr int CONV_BLOCKS = (128 * 128 + 128 * 64) / 256;

  k_zero_i32<<<(N + T - 1) / T, T, 0, stream>>>(counts, N);
  k_count_convW<<<CONV_BLOCKS + FB, T, 0, stream>>>(dst, counts, W1, W2, Wb1, Wb2, E);
  k_scan1<<<G, T, 0, stream>>>(counts, offsets, aux, N);
  k_scan3_dinv<<<(N + T - 1) / T, T, 0, stream>>>(offsets, aux, cursor, counts, dinv, N, E, G);
  k_fill_gemm1<<<FB + GB, T, 0, stream>>>(src, dst, cursor, esrc, E, FB, x, Wb1, dinv, h1s, N);
  k_aggemm<<<(N + 15) / 16, T, 0, stream>>>(h1s, dinv, b1, offsets, esrc, Wb2, h2s, N);
  k_agg2<<<(N + 31) / 32, T, 0, stream>>>(h2s, dinv, b2, offsets, esrc, out, N);
}